// Round 2
// baseline (2553.723 us; speedup 1.0000x reference)
//
#include <hip/hip_runtime.h>
#include <math.h>

// Problem constants (from reference)
#define Nn   100000
#define Ee   300000
#define FIN  128
#define Hdim 256
#define Ncls 40
#define Lnum 6

// ---------------- bf16 helpers (storage bf16, compute fp32) ----------------
__device__ __forceinline__ float bf2f(unsigned int u16) {
    unsigned int x = u16 << 16;
    return __builtin_bit_cast(float, x);
}
__device__ __forceinline__ unsigned short f2bf(float f) {
    unsigned int x = __builtin_bit_cast(unsigned int, f);
    x = (x + 0x7FFFu + ((x >> 16) & 1u)) >> 16;   // round-nearest-even
    return (unsigned short)x;
}
__device__ __forceinline__ void unpack2(unsigned int u, float& lo, float& hi) {
    lo = __builtin_bit_cast(float, u << 16);
    hi = __builtin_bit_cast(float, u & 0xFFFF0000u);
}
__device__ __forceinline__ unsigned int pack2(float a, float b) {
    return (unsigned int)f2bf(a) | ((unsigned int)f2bf(b) << 16);
}

// ---------------------------------------------------------------------------
// Graph preprocessing
// ---------------------------------------------------------------------------
__global__ void count_edges(const int* __restrict__ ei, int* __restrict__ cnt) {
    int e = blockIdx.x * blockDim.x + threadIdx.x;
    if (e < Ee) atomicAdd(&cnt[ei[Ee + e]], 1);   // row 1 of edge_index = dst
}

__global__ void scan_offsets(const int* __restrict__ cnt, int* __restrict__ offs, int n) {
    __shared__ int buf[1024];
    int t = threadIdx.x;
    const int chunk = (n + 1023) >> 10;
    int base = t * chunk;
    int s = 0;
    for (int i = 0; i < chunk; ++i) { int idx = base + i; if (idx < n) s += cnt[idx]; }
    buf[t] = s; __syncthreads();
    for (int off = 1; off < 1024; off <<= 1) {
        int v = buf[t];
        int add = (t >= off) ? buf[t - off] : 0;
        __syncthreads();
        buf[t] = v + add;
        __syncthreads();
    }
    int run = (t == 0) ? 0 : buf[t - 1];
    for (int i = 0; i < chunk; ++i) {
        int idx = base + i;
        if (idx < n) { offs[idx] = run; run += cnt[idx]; }
    }
    if (t == 1023) offs[n] = buf[1023];
}

__global__ void dinv_kernel(const int* __restrict__ cnt, float* __restrict__ dinvp) {
    int n = blockIdx.x * blockDim.x + threadIdx.x;
    if (n < Nn) dinvp[n] = rsqrtf((float)(cnt[n] + 1));
}

__global__ void fill_csr(const int* __restrict__ ei, const int* __restrict__ offs,
                         int* __restrict__ cur, const float* __restrict__ dinvp,
                         int* __restrict__ esrc, float* __restrict__ ew) {
    int e = blockIdx.x * blockDim.x + threadIdx.x;
    if (e >= Ee) return;
    int s = ei[e], d = ei[Ee + e];
    int p = offs[d] + atomicAdd(&cur[d], 1);
    esrc[p] = s;
    ew[p] = dinvp[s];
}

__global__ void softmax_res(const float* __restrict__ rw, float* __restrict__ wsoft) {
    if (threadIdx.x == 0) {
        float m = rw[0];
        for (int i = 1; i < Lnum; ++i) m = fmaxf(m, rw[i]);
        float e[Lnum]; float s = 0.f;
        for (int i = 0; i < Lnum; ++i) { e[i] = expf(rw[i] - m); s += e[i]; }
        for (int i = 0; i < Lnum; ++i) wsoft[i] = e[i] / s;
    }
}

// ---------------------------------------------------------------------------
// Aggregation (bf16 in/out, fp32 accum): T[n] = dinv[n]*(sum_e w_e*H[src] + dinv[n]*H[n])
// 128 threads/node, 2 features each (packed uint). Block 0 zeroes BN stats.
// ---------------------------------------------------------------------------
__global__ void agg_kernel(const unsigned short* __restrict__ Hin,
                           unsigned short* __restrict__ T,
                           const int* __restrict__ offs, const int* __restrict__ esrc,
                           const float* __restrict__ ew, const float* __restrict__ dinvp,
                           float* __restrict__ bnsum, float* __restrict__ bnsq) {
    int n = blockIdx.x, t = threadIdx.x;   // t < 128
    if (n == 0) { bnsum[t] = 0.f; bnsum[t + 128] = 0.f; bnsq[t] = 0.f; bnsq[t + 128] = 0.f; }
    int o0 = offs[n], o1 = offs[n + 1];
    float dn = dinvp[n];
    unsigned int u = *(const unsigned int*)&Hin[(size_t)n * Hdim + t * 2];
    float a0, a1; unpack2(u, a0, a1);
    a0 *= dn; a1 *= dn;
    for (int e = o0; e < o1; ++e) {
        int s = esrc[e];
        float w = ew[e];
        unsigned int us = *(const unsigned int*)&Hin[(size_t)s * Hdim + t * 2];
        float v0, v1; unpack2(us, v0, v1);
        a0 += w * v0; a1 += w * v1;
    }
    *(unsigned int*)&T[(size_t)n * Hdim + t * 2] = pack2(dn * a0, dn * a1);
}

// ---------------------------------------------------------------------------
// GEMM: C[M,256] = A[M,K] @ W[K,256] + bias (bf16 C; A fp32 or bf16 by template)
// BM=128 rows/block, 256 threads (16x16), thread tile 8x16. In-place safe.
// ---------------------------------------------------------------------------
#define BM 128
#define KC 32

template <bool A_BF16>
__global__ __launch_bounds__(256, 2) void gemm256(
    const void* __restrict__ Av, unsigned short* __restrict__ C,
    const float* __restrict__ W, const float* __restrict__ bias,
    int K, int nrows, float* __restrict__ bnsum, float* __restrict__ bnsq, int do_stats)
{
    __shared__ float Al[BM][KC + 1];
    __shared__ float Bl[KC * 256];

    const int t  = threadIdx.x;
    const int tx = t & 15, ty = t >> 4;
    const int r0 = blockIdx.x * BM;

    float acc[8][16];
#pragma unroll
    for (int i = 0; i < 8; ++i)
#pragma unroll
        for (int j = 0; j < 16; ++j) acc[i][j] = 0.f;

    for (int k0 = 0; k0 < K; k0 += KC) {
        __syncthreads();
        if (A_BF16) {
            const unsigned short* A = (const unsigned short*)Av;
            // 128 rows x 32 cols bf16 = 512 uint4, 2 per thread
#pragma unroll
            for (int q = 0; q < 2; ++q) {
                int qid = t + 256 * q;
                int row = qid >> 2, kq = qid & 3;
                uint4 g = make_uint4(0u, 0u, 0u, 0u);
                if (r0 + row < nrows)
                    g = *(const uint4*)&A[(size_t)(r0 + row) * K + k0 + kq * 8];
                float f0, f1;
                unpack2(g.x, f0, f1); Al[row][kq * 8 + 0] = f0; Al[row][kq * 8 + 1] = f1;
                unpack2(g.y, f0, f1); Al[row][kq * 8 + 2] = f0; Al[row][kq * 8 + 3] = f1;
                unpack2(g.z, f0, f1); Al[row][kq * 8 + 4] = f0; Al[row][kq * 8 + 5] = f1;
                unpack2(g.w, f0, f1); Al[row][kq * 8 + 6] = f0; Al[row][kq * 8 + 7] = f1;
            }
        } else {
            const float* A = (const float*)Av;
#pragma unroll
            for (int q = 0; q < 4; ++q) {
                int qid = t + 256 * q;
                int row = qid >> 3, kq = qid & 7;
                float4 g = make_float4(0.f, 0.f, 0.f, 0.f);
                if (r0 + row < nrows)
                    g = *(const float4*)&((const float*)A)[(size_t)(r0 + row) * K + k0 + kq * 4];
                Al[row][kq * 4 + 0] = g.x; Al[row][kq * 4 + 1] = g.y;
                Al[row][kq * 4 + 2] = g.z; Al[row][kq * 4 + 3] = g.w;
            }
        }
        // stage B: 32x256 fp32 = 2048 float4, 8 per thread
#pragma unroll
        for (int q = 0; q < 8; ++q) {
            int qid = t + 256 * q;
            int k = qid >> 6, c4 = qid & 63;
            *(float4*)&Bl[k * 256 + c4 * 4] = *(const float4*)&W[(size_t)(k0 + k) * 256 + c4 * 4];
        }
        __syncthreads();
#pragma unroll 4
        for (int kk = 0; kk < KC; ++kk) {
            float a[8];
#pragma unroll
            for (int j = 0; j < 8; ++j) a[j] = Al[ty * 8 + j][kk];
            float4 b[4];
#pragma unroll
            for (int j = 0; j < 4; ++j) b[j] = *(const float4*)&Bl[kk * 256 + tx * 16 + j * 4];
#pragma unroll
            for (int i = 0; i < 8; ++i) {
#pragma unroll
                for (int j = 0; j < 4; ++j) {
                    acc[i][j * 4 + 0] += a[i] * b[j].x;
                    acc[i][j * 4 + 1] += a[i] * b[j].y;
                    acc[i][j * 4 + 2] += a[i] * b[j].z;
                    acc[i][j * 4 + 3] += a[i] * b[j].w;
                }
            }
        }
    }

    // epilogue: + bias, store bf16 (in-place safe: all A reads done)
    float bv[16];
#pragma unroll
    for (int j = 0; j < 16; ++j) bv[j] = bias[tx * 16 + j];
#pragma unroll
    for (int i = 0; i < 8; ++i) {
        int r = r0 + ty * 8 + i;
        if (r < nrows) {
#pragma unroll
            for (int j = 0; j < 16; ++j) acc[i][j] += bv[j];
            uint4 o1, o2;
            o1.x = pack2(acc[i][0],  acc[i][1]);  o1.y = pack2(acc[i][2],  acc[i][3]);
            o1.z = pack2(acc[i][4],  acc[i][5]);  o1.w = pack2(acc[i][6],  acc[i][7]);
            o2.x = pack2(acc[i][8],  acc[i][9]);  o2.y = pack2(acc[i][10], acc[i][11]);
            o2.z = pack2(acc[i][12], acc[i][13]); o2.w = pack2(acc[i][14], acc[i][15]);
            *(uint4*)&C[(size_t)r * 256 + tx * 16]     = o1;
            *(uint4*)&C[(size_t)r * 256 + tx * 16 + 8] = o2;
        }
    }

    if (do_stats) {
        __syncthreads();
        Bl[t] = 0.f; Bl[256 + t] = 0.f;
        __syncthreads();
#pragma unroll
        for (int j = 0; j < 16; ++j) {
            float s = 0.f, q = 0.f;
#pragma unroll
            for (int i = 0; i < 8; ++i) {
                int r = r0 + ty * 8 + i;
                if (r < nrows) { float v = acc[i][j]; s += v; q += v * v; }
            }
            atomicAdd(&Bl[tx * 16 + j], s);
            atomicAdd(&Bl[256 + tx * 16 + j], q);
        }
        __syncthreads();
        atomicAdd(&bnsum[t], Bl[t]);
        atomicAdd(&bnsq[t], Bl[256 + t]);
    }
}

// ---------------------------------------------------------------------------
__global__ void bn_final(const float* __restrict__ bnsum, const float* __restrict__ bnsq,
                         const float* __restrict__ gamma, const float* __restrict__ beta,
                         float* __restrict__ scale, float* __restrict__ shiftv, float invn) {
    int t = threadIdx.x;
    float mean = bnsum[t] * invn;
    float var  = fmaxf(bnsq[t] * invn - mean * mean, 0.f);
    float rstd = rsqrtf(var + 1e-5f);
    float sc = gamma[t] * rstd;
    scale[t]  = sc;
    shiftv[t] = beta[t] - mean * sc;
}

// ---------------------------------------------------------------------------
// Apply: H = relu(T*scale+shift) + 0.2*X (+ 0.7*H);  M (+)= wsoft[l]*H
// 8 elements/thread via uint4 (bf16 x8)
// ---------------------------------------------------------------------------
__global__ void apply_kernel(const unsigned short* __restrict__ T,
                             const unsigned short* __restrict__ X,
                             unsigned short* __restrict__ Hb, unsigned short* __restrict__ M,
                             const float* __restrict__ scale, const float* __restrict__ shiftv,
                             const float* __restrict__ wsoft, int layer) {
    int idx = blockIdx.x * blockDim.x + threadIdx.x;   // uint4 index, Nn*32 total (exact)
    int c8 = idx & 31;                                  // 8-col group within row
    const float4* sc4 = (const float4*)scale;
    const float4* sh4 = (const float4*)shiftv;
    float4 sA = sc4[c8 * 2], sB = sc4[c8 * 2 + 1];
    float4 hA = sh4[c8 * 2], hB = sh4[c8 * 2 + 1];
    float sc[8] = {sA.x, sA.y, sA.z, sA.w, sB.x, sB.y, sB.z, sB.w};
    float sh[8] = {hA.x, hA.y, hA.z, hA.w, hB.x, hB.y, hB.z, hB.w};

    uint4 tv = ((const uint4*)T)[idx];
    uint4 xv = ((const uint4*)X)[idx];
    float tf[8], xf[8];
    unpack2(tv.x, tf[0], tf[1]); unpack2(tv.y, tf[2], tf[3]);
    unpack2(tv.z, tf[4], tf[5]); unpack2(tv.w, tf[6], tf[7]);
    unpack2(xv.x, xf[0], xf[1]); unpack2(xv.y, xf[2], xf[3]);
    unpack2(xv.z, xf[4], xf[5]); unpack2(xv.w, xf[6], xf[7]);

    float a[8];
#pragma unroll
    for (int k = 0; k < 8; ++k)
        a[k] = fmaxf(tf[k] * sc[k] + sh[k], 0.f) + 0.2f * xf[k];
    if (layer > 0) {
        uint4 hv = ((const uint4*)Hb)[idx];
        float hf[8];
        unpack2(hv.x, hf[0], hf[1]); unpack2(hv.y, hf[2], hf[3]);
        unpack2(hv.z, hf[4], hf[5]); unpack2(hv.w, hf[6], hf[7]);
#pragma unroll
        for (int k = 0; k < 8; ++k) a[k] += 0.7f * hf[k];
    }
    uint4 ho;
    ho.x = pack2(a[0], a[1]); ho.y = pack2(a[2], a[3]);
    ho.z = pack2(a[4], a[5]); ho.w = pack2(a[6], a[7]);
    ((uint4*)Hb)[idx] = ho;

    float wi = wsoft[layer];
    float m[8];
    if (layer == 0) {
#pragma unroll
        for (int k = 0; k < 8; ++k) m[k] = wi * a[k];
    } else {
        uint4 mv = ((const uint4*)M)[idx];
        float mf[8];
        unpack2(mv.x, mf[0], mf[1]); unpack2(mv.y, mf[2], mf[3]);
        unpack2(mv.z, mf[4], mf[5]); unpack2(mv.w, mf[6], mf[7]);
#pragma unroll
        for (int k = 0; k < 8; ++k) m[k] = mf[k] + wi * a[k];
    }
    uint4 mo;
    mo.x = pack2(m[0], m[1]); mo.y = pack2(m[2], m[3]);
    mo.z = pack2(m[4], m[5]); mo.w = pack2(m[6], m[7]);
    ((uint4*)M)[idx] = mo;
}

// ---------------------------------------------------------------------------
// Head: logits = M @ out_w + out_b ; log_softmax per row. 16 rows/block.
// ---------------------------------------------------------------------------
#define HBR 16
__global__ __launch_bounds__(128) void head_kernel(const unsigned short* __restrict__ M,
                                                   const float* __restrict__ out_w,
                                                   const float* __restrict__ out_b,
                                                   float* __restrict__ out) {
    __shared__ float wl[256 * 40];        // 40 KB
    __shared__ float rows[HBR * 257];
    int t = threadIdx.x;
    int r0 = blockIdx.x * HBR;
#pragma unroll
    for (int q = 0; q < 20; ++q) {
        int qid = t + 128 * q;
        *(float4*)&wl[qid * 4] = *(const float4*)&out_w[qid * 4];
    }
#pragma unroll
    for (int q = 0; q < 4; ++q) {         // 16 rows * 32 uint4 = 512, 4/thread
        int qid = t + 128 * q;
        int r = qid >> 5, c = qid & 31;
        uint4 g = *(const uint4*)&M[(size_t)(r0 + r) * 256 + c * 8];
        float f[8];
        unpack2(g.x, f[0], f[1]); unpack2(g.y, f[2], f[3]);
        unpack2(g.z, f[4], f[5]); unpack2(g.w, f[6], f[7]);
#pragma unroll
        for (int k = 0; k < 8; ++k) rows[r * 257 + c * 8 + k] = f[k];
    }
    __syncthreads();
    int r = t >> 3, g8 = t & 7, c0 = g8 * 5;
    float acc[5];
#pragma unroll
    for (int j = 0; j < 5; ++j) acc[j] = out_b[c0 + j];
    for (int k = 0; k < 256; ++k) {
        float m = rows[r * 257 + k];
#pragma unroll
        for (int j = 0; j < 5; ++j) acc[j] += m * wl[k * 40 + c0 + j];
    }
    float mx = acc[0];
#pragma unroll
    for (int j = 1; j < 5; ++j) mx = fmaxf(mx, acc[j]);
    for (int d = 1; d < 8; d <<= 1) mx = fmaxf(mx, __shfl_xor(mx, d));
    float s = 0.f;
#pragma unroll
    for (int j = 0; j < 5; ++j) s += expf(acc[j] - mx);
    for (int d = 1; d < 8; d <<= 1) s += __shfl_xor(s, d);
    float lse = mx + logf(s);
#pragma unroll
    for (int j = 0; j < 5; ++j)
        out[(size_t)(r0 + r) * 40 + c0 + j] = acc[j] - lse;
}

// ---------------------------------------------------------------------------
extern "C" void kernel_launch(void* const* d_in, const int* in_sizes, int n_in,
                              void* d_out, int out_size, void* d_ws, size_t ws_size,
                              hipStream_t stream)
{
    const float* x      = (const float*)d_in[0];
    const int*   ei     = (const int*)d_in[1];
    const float* w_in   = (const float*)d_in[2];
    const float* b_in   = (const float*)d_in[3];
    const float* conv_w = (const float*)d_in[4];
    const float* conv_b = (const float*)d_in[5];
    const float* gamma  = (const float*)d_in[6];
    const float* beta   = (const float*)d_in[7];
    const float* out_w  = (const float*)d_in[8];
    const float* out_b  = (const float*)d_in[9];
    const float* res_w  = (const float*)d_in[10];
    float* out = (float*)d_out;
    char* ws = (char*)d_ws;

    // workspace layout (16B-aligned slots); total ~209 MB
    int*   cnt    = (int*)  (ws + 0);        // 400,000
    int*   cursor = (int*)  (ws + 400000);   // 400,000
    int*   offs   = (int*)  (ws + 800000);   // 400,004
    float* dinvp  = (float*)(ws + 1200016);  // 400,000
    int*   esrc   = (int*)  (ws + 1600016);  // 1,200,000
    float* ew     = (float*)(ws + 2800016);  // 1,200,000
    float* bnsum  = (float*)(ws + 4000016);
    float* bnsq   = (float*)(ws + 4001040);
    float* scale  = (float*)(ws + 4002064);
    float* shiftv = (float*)(ws + 4003088);
    float* wsoft  = (float*)(ws + 4004112);
    unsigned short* X  = (unsigned short*)(ws + 4194304);   // N*H bf16 = 51.2 MB each
    unsigned short* Hb = X  + (size_t)Nn * Hdim;
    unsigned short* T  = Hb + (size_t)Nn * Hdim;
    unsigned short* M  = T  + (size_t)Nn * Hdim;

    hipMemsetAsync(cnt, 0, 800000, stream);  // cnt + cursor

    count_edges<<<(Ee + 255) / 256, 256, 0, stream>>>(ei, cnt);
    scan_offsets<<<1, 1024, 0, stream>>>(cnt, offs, Nn);
    dinv_kernel<<<(Nn + 255) / 256, 256, 0, stream>>>(cnt, dinvp);
    fill_csr<<<(Ee + 255) / 256, 256, 0, stream>>>(ei, offs, cursor, dinvp, esrc, ew);
    softmax_res<<<1, 64, 0, stream>>>(res_w, wsoft);

    // input fc: X = x @ w_in + b_in  (fp32 A -> bf16 C)
    gemm256<false><<<(Nn + BM - 1) / BM, 256, 0, stream>>>(x, X, w_in, b_in, FIN, Nn,
                                                           nullptr, nullptr, 0);

    for (int i = 0; i < Lnum; ++i) {
        agg_kernel<<<Nn, 128, 0, stream>>>(i == 0 ? X : Hb, T, offs, esrc, ew, dinvp,
                                           bnsum, bnsq);
        gemm256<true><<<(Nn + BM - 1) / BM, 256, 0, stream>>>(T, T,
                                                              conv_w + (size_t)i * Hdim * Hdim,
                                                              conv_b + (size_t)i * Hdim,
                                                              Hdim, Nn, bnsum, bnsq, 1);
        bn_final<<<1, 256, 0, stream>>>(bnsum, bnsq, gamma + (size_t)i * Hdim,
                                        beta + (size_t)i * Hdim, scale, shiftv,
                                        1.0f / (float)Nn);
        apply_kernel<<<(Nn * 32) / 256, 256, 0, stream>>>(T, X, Hb, M, scale, shiftv,
                                                          wsoft, i);
    }

    head_kernel<<<Nn / HBR, 128, 0, stream>>>(M, out_w, out_b, out);
}

// Round 3
// 1524.492 us; speedup vs baseline: 1.6751x; 1.6751x over previous
//
#include <hip/hip_runtime.h>
#include <math.h>

// Problem constants (from reference)
#define Nn   100000
#define Ee   300000
#define FIN  128
#define Hdim 256
#define Ncls 40
#define Lnum 6

typedef __attribute__((ext_vector_type(8))) short bf16x8;
typedef __attribute__((ext_vector_type(4))) float f32x4;

// ---------------- bf16 helpers (storage bf16, compute fp32) ----------------
__device__ __forceinline__ float bf2f(unsigned int u16) {
    unsigned int x = u16 << 16;
    return __builtin_bit_cast(float, x);
}
__device__ __forceinline__ unsigned short f2bf(float f) {
    unsigned int x = __builtin_bit_cast(unsigned int, f);
    x = (x + 0x7FFFu + ((x >> 16) & 1u)) >> 16;   // round-nearest-even
    return (unsigned short)x;
}
__device__ __forceinline__ void unpack2(unsigned int u, float& lo, float& hi) {
    lo = __builtin_bit_cast(float, u << 16);
    hi = __builtin_bit_cast(float, u & 0xFFFF0000u);
}
__device__ __forceinline__ unsigned int pack2(float a, float b) {
    return (unsigned int)f2bf(a) | ((unsigned int)f2bf(b) << 16);
}

// ---------------------------------------------------------------------------
// Graph preprocessing
// ---------------------------------------------------------------------------
__global__ void count_edges(const int* __restrict__ ei, int* __restrict__ cnt) {
    int e = blockIdx.x * blockDim.x + threadIdx.x;
    if (e < Ee) atomicAdd(&cnt[ei[Ee + e]], 1);   // row 1 of edge_index = dst
}

__global__ void scan_offsets(const int* __restrict__ cnt, int* __restrict__ offs, int n) {
    __shared__ int buf[1024];
    int t = threadIdx.x;
    const int chunk = (n + 1023) >> 10;
    int base = t * chunk;
    int s = 0;
    for (int i = 0; i < chunk; ++i) { int idx = base + i; if (idx < n) s += cnt[idx]; }
    buf[t] = s; __syncthreads();
    for (int off = 1; off < 1024; off <<= 1) {
        int v = buf[t];
        int add = (t >= off) ? buf[t - off] : 0;
        __syncthreads();
        buf[t] = v + add;
        __syncthreads();
    }
    int run = (t == 0) ? 0 : buf[t - 1];
    for (int i = 0; i < chunk; ++i) {
        int idx = base + i;
        if (idx < n) { offs[idx] = run; run += cnt[idx]; }
    }
    if (t == 1023) offs[n] = buf[1023];
}

__global__ void dinv_kernel(const int* __restrict__ cnt, float* __restrict__ dinvp) {
    int n = blockIdx.x * blockDim.x + threadIdx.x;
    if (n < Nn) dinvp[n] = rsqrtf((float)(cnt[n] + 1));
}

__global__ void fill_csr(const int* __restrict__ ei, const int* __restrict__ offs,
                         int* __restrict__ cur, const float* __restrict__ dinvp,
                         int* __restrict__ esrc, float* __restrict__ ew) {
    int e = blockIdx.x * blockDim.x + threadIdx.x;
    if (e >= Ee) return;
    int s = ei[e], d = ei[Ee + e];
    int p = offs[d] + atomicAdd(&cur[d], 1);
    esrc[p] = s;
    ew[p] = dinvp[s];
}

__global__ void softmax_res(const float* __restrict__ rw, float* __restrict__ wsoft) {
    if (threadIdx.x == 0) {
        float m = rw[0];
        for (int i = 1; i < Lnum; ++i) m = fmaxf(m, rw[i]);
        float e[Lnum]; float s = 0.f;
        for (int i = 0; i < Lnum; ++i) { e[i] = expf(rw[i] - m); s += e[i]; }
        for (int i = 0; i < Lnum; ++i) wsoft[i] = e[i] / s;
    }
}

// ---------------------------------------------------------------------------
// Weight split+transpose: W[K][256] fp32 -> Whi/Wlo [256][K] bf16 (hi + residual)
// ---------------------------------------------------------------------------
__global__ void split_w(const float* __restrict__ W, unsigned short* __restrict__ Whi,
                        unsigned short* __restrict__ Wlo, int K) {
    int id = blockIdx.x * blockDim.x + threadIdx.x;
    if (id >= K * 256) return;
    int k = id >> 8, n = id & 255;            // coalesced read over n
    float w = W[id];
    unsigned short hi = f2bf(w);
    unsigned short lo = f2bf(w - bf2f(hi));
    Whi[n * K + k] = hi;
    Wlo[n * K + k] = lo;
}

// x fp32 -> bf16 (8 elems/thread)
__global__ void cvt_bf16(const float* __restrict__ src, unsigned short* __restrict__ dst, int n8) {
    int i = blockIdx.x * blockDim.x + threadIdx.x;
    if (i >= n8) return;
    float4 a = ((const float4*)src)[i * 2];
    float4 b = ((const float4*)src)[i * 2 + 1];
    uint4 o;
    o.x = pack2(a.x, a.y); o.y = pack2(a.z, a.w);
    o.z = pack2(b.x, b.y); o.w = pack2(b.z, b.w);
    ((uint4*)dst)[i] = o;
}

// ---------------------------------------------------------------------------
// Aggregation (bf16 in/out, fp32 accum): T[n] = dinv[n]*(sum_e w_e*H[src] + dinv[n]*H[n])
// 128 threads/node, 2 features each. Block 0 zeroes BN stats.
// ---------------------------------------------------------------------------
__global__ void agg_kernel(const unsigned short* __restrict__ Hin,
                           unsigned short* __restrict__ T,
                           const int* __restrict__ offs, const int* __restrict__ esrc,
                           const float* __restrict__ ew, const float* __restrict__ dinvp,
                           float* __restrict__ bnsum, float* __restrict__ bnsq) {
    int n = blockIdx.x, t = threadIdx.x;   // t < 128
    if (n == 0) { bnsum[t] = 0.f; bnsum[t + 128] = 0.f; bnsq[t] = 0.f; bnsq[t + 128] = 0.f; }
    int o0 = offs[n], o1 = offs[n + 1];
    float dn = dinvp[n];
    unsigned int u = *(const unsigned int*)&Hin[(size_t)n * Hdim + t * 2];
    float a0, a1; unpack2(u, a0, a1);
    a0 *= dn; a1 *= dn;
    for (int e = o0; e < o1; ++e) {
        int s = esrc[e];
        float w = ew[e];
        unsigned int us = *(const unsigned int*)&Hin[(size_t)s * Hdim + t * 2];
        float v0, v1; unpack2(us, v0, v1);
        a0 += w * v0; a1 += w * v1;
    }
    *(unsigned int*)&T[(size_t)n * Hdim + t * 2] = pack2(dn * a0, dn * a1);
}

// ---------------------------------------------------------------------------
// MFMA GEMM: C[M,256] = A[M,K] @ (Whi+Wlo)[K,256] + bias  (all bf16 storage,
// fp32 accumulate; W given transposed [256][K] as hi/lo split).
// Block: 128 rows x 256 cols, 512 threads = 8 waves, wave = 64x64 quadrant,
// 4x4 tiles of mfma_f32_16x16x32_bf16. LDS rows padded to 40 bf16 (80B) ->
// b128 frag reads are 2-way bank-aliased (free). In-place safe (full-N block).
// ---------------------------------------------------------------------------
__global__ __launch_bounds__(512) void gemm_mfma(
    const unsigned short* __restrict__ A, unsigned short* __restrict__ C,
    const unsigned short* __restrict__ Whi, const unsigned short* __restrict__ Wlo,
    const float* __restrict__ bias, int K, int nrows,
    float* __restrict__ bnsum, float* __restrict__ bnsq, int do_stats)
{
    __shared__ unsigned short At[128 * 40];   // 10 KB
    __shared__ unsigned short Bh[256 * 40];   // 20 KB
    __shared__ unsigned short Bl[256 * 40];   // 20 KB
    __shared__ float lsum[256];
    __shared__ float lsq[256];

    const int t    = threadIdx.x;
    const int lane = t & 63, wid = t >> 6;
    const int ln   = lane & 15, quad = lane >> 4;
    const int r64  = (wid >> 2) * 64, c64 = (wid & 3) * 64;
    const int r0   = blockIdx.x * 128;

    if (t < 256) { lsum[t] = 0.f; lsq[t] = 0.f; }

    f32x4 acc[4][4];
#pragma unroll
    for (int i = 0; i < 4; ++i)
#pragma unroll
        for (int j = 0; j < 4; ++j) acc[i][j] = (f32x4){0.f, 0.f, 0.f, 0.f};

    for (int k0 = 0; k0 < K; k0 += 32) {
        __syncthreads();
        {   // stage A: 128 rows x 32 k bf16 = 512 uint4, 1/thread
            int row = t >> 2, kq = t & 3;
            uint4 g = make_uint4(0u, 0u, 0u, 0u);
            if (r0 + row < nrows)
                g = *(const uint4*)&A[(size_t)(r0 + row) * K + k0 + kq * 8];
            *(uint4*)&At[row * 40 + kq * 8] = g;
        }
#pragma unroll
        for (int q = 0; q < 2; ++q) {   // stage Bhi/Blo: 256 rows x 32 k each
            int idx = t + 512 * q;
            int row = idx >> 2, kq = idx & 3;
            *(uint4*)&Bh[row * 40 + kq * 8] = *(const uint4*)&Whi[(size_t)row * K + k0 + kq * 8];
            *(uint4*)&Bl[row * 40 + kq * 8] = *(const uint4*)&Wlo[(size_t)row * K + k0 + kq * 8];
        }
        __syncthreads();

        bf16x8 af[4], bh[4], bl[4];
#pragma unroll
        for (int rt = 0; rt < 4; ++rt)
            af[rt] = *(const bf16x8*)&At[(r64 + rt * 16 + ln) * 40 + quad * 8];
#pragma unroll
        for (int ct = 0; ct < 4; ++ct) {
            bh[ct] = *(const bf16x8*)&Bh[(c64 + ct * 16 + ln) * 40 + quad * 8];
            bl[ct] = *(const bf16x8*)&Bl[(c64 + ct * 16 + ln) * 40 + quad * 8];
        }
#pragma unroll
        for (int rt = 0; rt < 4; ++rt)
#pragma unroll
            for (int ct = 0; ct < 4; ++ct) {
                acc[rt][ct] = __builtin_amdgcn_mfma_f32_16x16x32_bf16(af[rt], bh[ct], acc[rt][ct], 0, 0, 0);
                acc[rt][ct] = __builtin_amdgcn_mfma_f32_16x16x32_bf16(af[rt], bl[ct], acc[rt][ct], 0, 0, 0);
            }
    }

    // epilogue: +bias, bf16 store, fused BN stats (pad rows excluded)
    // C/D layout (m89-verified): col = lane&15, row = quad*4 + reg
#pragma unroll
    for (int ct = 0; ct < 4; ++ct) {
        int col = c64 + ct * 16 + ln;
        float bc = bias[col];
        float s = 0.f, qq = 0.f;
#pragma unroll
        for (int rt = 0; rt < 4; ++rt) {
#pragma unroll
            for (int v = 0; v < 4; ++v) {
                int row = r0 + r64 + rt * 16 + quad * 4 + v;
                float val = acc[rt][ct][v] + bc;
                if (row < nrows) {
                    C[(size_t)row * 256 + col] = f2bf(val);
                    s += val; qq += val * val;
                }
            }
        }
        if (do_stats) {
            s  += __shfl_xor(s, 16);  s  += __shfl_xor(s, 32);
            qq += __shfl_xor(qq, 16); qq += __shfl_xor(qq, 32);
            if (quad == 0) { atomicAdd(&lsum[col], s); atomicAdd(&lsq[col], qq); }
        }
    }
    if (do_stats) {
        __syncthreads();
        if (t < 256) { atomicAdd(&bnsum[t], lsum[t]); atomicAdd(&bnsq[t], lsq[t]); }
    }
}

// ---------------------------------------------------------------------------
__global__ void bn_final(const float* __restrict__ bnsum, const float* __restrict__ bnsq,
                         const float* __restrict__ gamma, const float* __restrict__ beta,
                         float* __restrict__ scale, float* __restrict__ shiftv, float invn) {
    int t = threadIdx.x;
    float mean = bnsum[t] * invn;
    float var  = fmaxf(bnsq[t] * invn - mean * mean, 0.f);
    float rstd = rsqrtf(var + 1e-5f);
    float sc = gamma[t] * rstd;
    scale[t]  = sc;
    shiftv[t] = beta[t] - mean * sc;
}

// ---------------------------------------------------------------------------
// Apply: H = relu(T*scale+shift) + 0.2*X (+ 0.7*H);  M (+)= wsoft[l]*H
// ---------------------------------------------------------------------------
__global__ void apply_kernel(const unsigned short* __restrict__ T,
                             const unsigned short* __restrict__ X,
                             unsigned short* __restrict__ Hb, unsigned short* __restrict__ M,
                             const float* __restrict__ scale, const float* __restrict__ shiftv,
                             const float* __restrict__ wsoft, int layer) {
    int idx = blockIdx.x * blockDim.x + threadIdx.x;   // uint4 index, Nn*32 total
    int c8 = idx & 31;
    const float4* sc4 = (const float4*)scale;
    const float4* sh4 = (const float4*)shiftv;
    float4 sA = sc4[c8 * 2], sB = sc4[c8 * 2 + 1];
    float4 hA = sh4[c8 * 2], hB = sh4[c8 * 2 + 1];
    float sc[8] = {sA.x, sA.y, sA.z, sA.w, sB.x, sB.y, sB.z, sB.w};
    float sh[8] = {hA.x, hA.y, hA.z, hA.w, hB.x, hB.y, hB.z, hB.w};

    uint4 tv = ((const uint4*)T)[idx];
    uint4 xv = ((const uint4*)X)[idx];
    float tf[8], xf[8];
    unpack2(tv.x, tf[0], tf[1]); unpack2(tv.y, tf[2], tf[3]);
    unpack2(tv.z, tf[4], tf[5]); unpack2(tv.w, tf[6], tf[7]);
    unpack2(xv.x, xf[0], xf[1]); unpack2(xv.y, xf[2], xf[3]);
    unpack2(xv.z, xf[4], xf[5]); unpack2(xv.w, xf[6], xf[7]);

    float a[8];
#pragma unroll
    for (int k = 0; k < 8; ++k)
        a[k] = fmaxf(tf[k] * sc[k] + sh[k], 0.f) + 0.2f * xf[k];
    if (layer > 0) {
        uint4 hv = ((const uint4*)Hb)[idx];
        float hf[8];
        unpack2(hv.x, hf[0], hf[1]); unpack2(hv.y, hf[2], hf[3]);
        unpack2(hv.z, hf[4], hf[5]); unpack2(hv.w, hf[6], hf[7]);
#pragma unroll
        for (int k = 0; k < 8; ++k) a[k] += 0.7f * hf[k];
    }
    uint4 ho;
    ho.x = pack2(a[0], a[1]); ho.y = pack2(a[2], a[3]);
    ho.z = pack2(a[4], a[5]); ho.w = pack2(a[6], a[7]);
    ((uint4*)Hb)[idx] = ho;

    float wi = wsoft[layer];
    float m[8];
    if (layer == 0) {
#pragma unroll
        for (int k = 0; k < 8; ++k) m[k] = wi * a[k];
    } else {
        uint4 mv = ((const uint4*)M)[idx];
        float mf[8];
        unpack2(mv.x, mf[0], mf[1]); unpack2(mv.y, mf[2], mf[3]);
        unpack2(mv.z, mf[4], mf[5]); unpack2(mv.w, mf[6], mf[7]);
#pragma unroll
        for (int k = 0; k < 8; ++k) m[k] = mf[k] + wi * a[k];
    }
    uint4 mo;
    mo.x = pack2(m[0], m[1]); mo.y = pack2(m[2], m[3]);
    mo.z = pack2(m[4], m[5]); mo.w = pack2(m[6], m[7]);
    ((uint4*)M)[idx] = mo;
}

// ---------------------------------------------------------------------------
// Head: logits = M @ out_w + out_b ; log_softmax per row. 16 rows/block.
// ---------------------------------------------------------------------------
#define HBR 16
__global__ __launch_bounds__(128) void head_kernel(const unsigned short* __restrict__ M,
                                                   const float* __restrict__ out_w,
                                                   const float* __restrict__ out_b,
                                                   float* __restrict__ out) {
    __shared__ float wl[256 * 40];
    __shared__ float rows[HBR * 257];
    int t = threadIdx.x;
    int r0 = blockIdx.x * HBR;
#pragma unroll
    for (int q = 0; q < 20; ++q) {
        int qid = t + 128 * q;
        *(float4*)&wl[qid * 4] = *(const float4*)&out_w[qid * 4];
    }
#pragma unroll
    for (int q = 0; q < 4; ++q) {
        int qid = t + 128 * q;
        int r = qid >> 5, c = qid & 31;
        uint4 g = *(const uint4*)&M[(size_t)(r0 + r) * 256 + c * 8];
        float f[8];
        unpack2(g.x, f[0], f[1]); unpack2(g.y, f[2], f[3]);
        unpack2(g.z, f[4], f[5]); unpack2(g.w, f[6], f[7]);
#pragma unroll
        for (int k = 0; k < 8; ++k) rows[r * 257 + c * 8 + k] = f[k];
    }
    __syncthreads();
    int r = t >> 3, g8 = t & 7, c0 = g8 * 5;
    float acc[5];
#pragma unroll
    for (int j = 0; j < 5; ++j) acc[j] = out_b[c0 + j];
    for (int k = 0; k < 256; ++k) {
        float m = rows[r * 257 + k];
#pragma unroll
        for (int j = 0; j < 5; ++j) acc[j] += m * wl[k * 40 + c0 + j];
    }
    float mx = acc[0];
#pragma unroll
    for (int j = 1; j < 5; ++j) mx = fmaxf(mx, acc[j]);
    for (int d = 1; d < 8; d <<= 1) mx = fmaxf(mx, __shfl_xor(mx, d));
    float s = 0.f;
#pragma unroll
    for (int j = 0; j < 5; ++j) s += expf(acc[j] - mx);
    for (int d = 1; d < 8; d <<= 1) s += __shfl_xor(s, d);
    float lse = mx + logf(s);
#pragma unroll
    for (int j = 0; j < 5; ++j)
        out[(size_t)(r0 + r) * 40 + c0 + j] = acc[j] - lse;
}

// ---------------------------------------------------------------------------
extern "C" void kernel_launch(void* const* d_in, const int* in_sizes, int n_in,
                              void* d_out, int out_size, void* d_ws, size_t ws_size,
                              hipStream_t stream)
{
    const float* x      = (const float*)d_in[0];
    const int*   ei     = (const int*)d_in[1];
    const float* w_in   = (const float*)d_in[2];
    const float* b_in   = (const float*)d_in[3];
    const float* conv_w = (const float*)d_in[4];
    const float* conv_b = (const float*)d_in[5];
    const float* gamma  = (const float*)d_in[6];
    const float* beta   = (const float*)d_in[7];
    const float* out_w  = (const float*)d_in[8];
    const float* out_b  = (const float*)d_in[9];
    const float* res_w  = (const float*)d_in[10];
    float* out = (float*)d_out;
    char* ws = (char*)d_ws;

    // workspace layout (total ~210.5 MB)
    int*   cnt    = (int*)  (ws + 0);
    int*   cursor = (int*)  (ws + 400000);
    int*   offs   = (int*)  (ws + 800000);
    float* dinvp  = (float*)(ws + 1200016);
    int*   esrc   = (int*)  (ws + 1600016);
    float* ew     = (float*)(ws + 2800016);
    float* bnsum  = (float*)(ws + 4000016);
    float* bnsq   = (float*)(ws + 4001040);
    float* scale  = (float*)(ws + 4002064);
    float* shiftv = (float*)(ws + 4003088);
    float* wsoft  = (float*)(ws + 4004112);
    unsigned short* Whi = (unsigned short*)(ws + 4004352);   // [L][256][256] bf16
    unsigned short* Wlo = (unsigned short*)(ws + 4790784);
    unsigned short* Fhi = (unsigned short*)(ws + 5577216);   // [256][128] bf16
    unsigned short* Flo = (unsigned short*)(ws + 5642752);
    unsigned short* X   = (unsigned short*)(ws + 5708288);   // N*H bf16 = 51.2 MB each
    unsigned short* Hb  = X  + (size_t)Nn * Hdim;
    unsigned short* T   = Hb + (size_t)Nn * Hdim;
    unsigned short* M   = T  + (size_t)Nn * Hdim;
    unsigned short* xbf = M;   // scratch alias: fc input, dead before M first written

    hipMemsetAsync(cnt, 0, 800000, stream);  // cnt + cursor

    count_edges<<<(Ee + 255) / 256, 256, 0, stream>>>(ei, cnt);
    scan_offsets<<<1, 1024, 0, stream>>>(cnt, offs, Nn);
    dinv_kernel<<<(Nn + 255) / 256, 256, 0, stream>>>(cnt, dinvp);
    fill_csr<<<(Ee + 255) / 256, 256, 0, stream>>>(ei, offs, cursor, dinvp, esrc, ew);
    softmax_res<<<1, 64, 0, stream>>>(res_w, wsoft);

    // weight split+transpose (runs every call; ~1.8 MB total traffic)
    for (int i = 0; i < Lnum; ++i)
        split_w<<<(Hdim * 256 + 255) / 256, 256, 0, stream>>>(
            conv_w + (size_t)i * Hdim * Hdim,
            Whi + (size_t)i * Hdim * Hdim, Wlo + (size_t)i * Hdim * Hdim, Hdim);
    split_w<<<(FIN * 256 + 255) / 256, 256, 0, stream>>>(w_in, Fhi, Flo, FIN);
    cvt_bf16<<<(Nn * FIN / 8 + 255) / 256, 256, 0, stream>>>(x, xbf, Nn * FIN / 8);

    const int gblocks = (Nn + 127) / 128;   // 782
    // input fc: X = xbf @ w_in + b_in
    gemm_mfma<<<gblocks, 512, 0, stream>>>(xbf, X, Fhi, Flo, b_in, FIN, Nn,
                                           nullptr, nullptr, 0);

    for (int i = 0; i < Lnum; ++i) {
        agg_kernel<<<Nn, 128, 0, stream>>>(i == 0 ? X : Hb, T, offs, esrc, ew, dinvp,
                                           bnsum, bnsq);
        gemm_mfma<<<gblocks, 512, 0, stream>>>(T, T,
                                               Whi + (size_t)i * Hdim * Hdim,
                                               Wlo + (size_t)i * Hdim * Hdim,
                                               conv_b + (size_t)i * Hdim,
                                               Hdim, Nn, bnsum, bnsq, 1);
        bn_final<<<1, 256, 0, stream>>>(bnsum, bnsq, gamma + (size_t)i * Hdim,
                                        beta + (size_t)i * Hdim, scale, shiftv,
                                        1.0f / (float)Nn);
        apply_kernel<<<(Nn * 32) / 256, 256, 0, stream>>>(T, X, Hb, M, scale, shiftv,
                                                          wsoft, i);
    }

    head_kernel<<<Nn / HBR, 128, 0, stream>>>(M, out_w, out_b, out);
}

// Round 4
// 1387.971 us; speedup vs baseline: 1.8399x; 1.0984x over previous
//
#include <hip/hip_runtime.h>
#include <math.h>

// Problem constants (from reference)
#define Nn   100000
#define Ee   300000
#define FIN  128
#define Hdim 256
#define Ncls 40
#define Lnum 6
#define SCAN_B 98   // ceil(Nn/1024)

typedef __attribute__((ext_vector_type(8))) short bf16x8;
typedef __attribute__((ext_vector_type(4))) float f32x4;

// ---------------- bf16 helpers (storage bf16, compute fp32) ----------------
__device__ __forceinline__ float bf2f(unsigned int u16) {
    unsigned int x = u16 << 16;
    return __builtin_bit_cast(float, x);
}
__device__ __forceinline__ unsigned short f2bf(float f) {
    unsigned int x = __builtin_bit_cast(unsigned int, f);
    x = (x + 0x7FFFu + ((x >> 16) & 1u)) >> 16;   // round-nearest-even
    return (unsigned short)x;
}
__device__ __forceinline__ void unpack2(unsigned int u, float& lo, float& hi) {
    lo = __builtin_bit_cast(float, u << 16);
    hi = __builtin_bit_cast(float, u & 0xFFFF0000u);
}
__device__ __forceinline__ unsigned int pack2(float a, float b) {
    return (unsigned int)f2bf(a) | ((unsigned int)f2bf(b) << 16);
}

// ---------------------------------------------------------------------------
// Graph preprocessing
// ---------------------------------------------------------------------------
__global__ void count_edges(const int* __restrict__ ei, int* __restrict__ cnt) {
    int e = blockIdx.x * blockDim.x + threadIdx.x;
    if (e < Ee) atomicAdd(&cnt[ei[Ee + e]], 1);   // row 1 of edge_index = dst
}

// Parallel scan, phase 1: per-block inclusive scan of 1024 counts + block total
__global__ void scan_block(const int* __restrict__ cnt, int* __restrict__ iscan,
                           int* __restrict__ btot) {
    __shared__ int buf[1024];
    int t = threadIdx.x;
    int g = blockIdx.x * 1024 + t;
    int v = (g < Nn) ? cnt[g] : 0;
    buf[t] = v; __syncthreads();
    for (int off = 1; off < 1024; off <<= 1) {
        int x = buf[t];
        int a = (t >= off) ? buf[t - off] : 0;
        __syncthreads();
        buf[t] = x + a;
        __syncthreads();
    }
    if (g < Nn) iscan[g] = buf[t];
    if (t == 1023) btot[blockIdx.x] = buf[1023];
}

// phase 2: exclusive scan of the 98 block totals (single tiny block)
__global__ void scan_tops(const int* __restrict__ btot, int* __restrict__ bpref) {
    __shared__ int b[128];
    int t = threadIdx.x;
    int v = (t < SCAN_B) ? btot[t] : 0;
    b[t] = v; __syncthreads();
    for (int off = 1; off < 128; off <<= 1) {
        int x = b[t];
        int a = (t >= off) ? b[t - off] : 0;
        __syncthreads();
        b[t] = x + a;
        __syncthreads();
    }
    if (t < SCAN_B) bpref[t] = b[t] - v;   // exclusive
}

// phase 3: exclusive node offsets + dinv (fused — cnt already in hand)
__global__ void scan_final(const int* __restrict__ cnt, const int* __restrict__ iscan,
                           const int* __restrict__ bpref, int* __restrict__ offs,
                           float* __restrict__ dinvp) {
    int g = blockIdx.x * 1024 + threadIdx.x;
    if (g < Nn) {
        int c = cnt[g];
        offs[g] = bpref[blockIdx.x] + iscan[g] - c;
        dinvp[g] = rsqrtf((float)(c + 1));    // deg = in-deg + self-loop
    }
    if (g == 0) offs[Nn] = Ee;
}

__global__ void fill_csr(const int* __restrict__ ei, const int* __restrict__ offs,
                         int* __restrict__ cur, const float* __restrict__ dinvp,
                         int* __restrict__ esrc, float* __restrict__ ew) {
    int e = blockIdx.x * blockDim.x + threadIdx.x;
    if (e >= Ee) return;
    int s = ei[e], d = ei[Ee + e];
    int p = offs[d] + atomicAdd(&cur[d], 1);
    esrc[p] = s;
    ew[p] = dinvp[s];
}

// ---------------------------------------------------------------------------
// Weight split+transpose (all 6 conv layers in one dispatch):
// W[l][k][n] fp32 -> Whi/Wlo [l][n][k] bf16 (hi + residual)
// ---------------------------------------------------------------------------
__global__ void split_w_all(const float* __restrict__ W, unsigned short* __restrict__ Whi,
                            unsigned short* __restrict__ Wlo) {
    int id = blockIdx.x * blockDim.x + threadIdx.x;   // Lnum*256*256 total
    int l = id >> 16, within = id & 65535;
    int k = within >> 8, n = within & 255;
    float w = W[id];
    unsigned short hi = f2bf(w);
    unsigned short lo = f2bf(w - bf2f(hi));
    Whi[l * 65536 + n * 256 + k] = hi;
    Wlo[l * 65536 + n * 256 + k] = lo;
}

__global__ void split_w(const float* __restrict__ W, unsigned short* __restrict__ Whi,
                        unsigned short* __restrict__ Wlo, int K) {
    int id = blockIdx.x * blockDim.x + threadIdx.x;
    if (id >= K * 256) return;
    int k = id >> 8, n = id & 255;
    float w = W[id];
    unsigned short hi = f2bf(w);
    unsigned short lo = f2bf(w - bf2f(hi));
    Whi[n * K + k] = hi;
    Wlo[n * K + k] = lo;
}

// x fp32 -> bf16 (8 elems/thread)
__global__ void cvt_bf16(const float* __restrict__ src, unsigned short* __restrict__ dst, int n8) {
    int i = blockIdx.x * blockDim.x + threadIdx.x;
    if (i >= n8) return;
    float4 a = ((const float4*)src)[i * 2];
    float4 b = ((const float4*)src)[i * 2 + 1];
    uint4 o;
    o.x = pack2(a.x, a.y); o.y = pack2(a.z, a.w);
    o.z = pack2(b.x, b.y); o.w = pack2(b.z, b.w);
    ((uint4*)dst)[i] = o;
}

// ---------------------------------------------------------------------------
// Aggregation (bf16 in/out, fp32 accum): T[n] = dinv[n]*(sum_e w_e*H[src] + dinv[n]*H[n])
// 128 threads/node, 2 features each. Block 0 zeroes BN stats.
// ---------------------------------------------------------------------------
__global__ void agg_kernel(const unsigned short* __restrict__ Hin,
                           unsigned short* __restrict__ T,
                           const int* __restrict__ offs, const int* __restrict__ esrc,
                           const float* __restrict__ ew, const float* __restrict__ dinvp,
                           float* __restrict__ bnsum, float* __restrict__ bnsq) {
    int n = blockIdx.x, t = threadIdx.x;   // t < 128
    if (n == 0) { bnsum[t] = 0.f; bnsum[t + 128] = 0.f; bnsq[t] = 0.f; bnsq[t + 128] = 0.f; }
    int o0 = offs[n], o1 = offs[n + 1];
    float dn = dinvp[n];
    unsigned int u = *(const unsigned int*)&Hin[(size_t)n * Hdim + t * 2];
    float a0, a1; unpack2(u, a0, a1);
    a0 *= dn; a1 *= dn;
    for (int e = o0; e < o1; ++e) {
        int s = esrc[e];
        float w = ew[e];
        unsigned int us = *(const unsigned int*)&Hin[(size_t)s * Hdim + t * 2];
        float v0, v1; unpack2(us, v0, v1);
        a0 += w * v0; a1 += w * v1;
    }
    *(unsigned int*)&T[(size_t)n * Hdim + t * 2] = pack2(dn * a0, dn * a1);
}

// ---------------------------------------------------------------------------
// MFMA GEMM: C[M,256] = A[M,K] @ (Whi+Wlo)[K,256] + bias  (all bf16 storage,
// fp32 accumulate; W given transposed [256][K] as hi/lo split).
// Block: 128 rows x 256 cols, 512 threads = 8 waves, wave = 64x64 quadrant,
// 4x4 tiles of mfma_f32_16x16x32_bf16. In-place safe (full-N block).
// ---------------------------------------------------------------------------
__global__ __launch_bounds__(512) void gemm_mfma(
    const unsigned short* __restrict__ A, unsigned short* __restrict__ C,
    const unsigned short* __restrict__ Whi, const unsigned short* __restrict__ Wlo,
    const float* __restrict__ bias, int K, int nrows,
    float* __restrict__ bnsum, float* __restrict__ bnsq, int do_stats)
{
    __shared__ unsigned short At[128 * 40];   // 10 KB
    __shared__ unsigned short Bh[256 * 40];   // 20 KB
    __shared__ unsigned short Bl[256 * 40];   // 20 KB
    __shared__ float lsum[256];
    __shared__ float lsq[256];

    const int t    = threadIdx.x;
    const int lane = t & 63, wid = t >> 6;
    const int ln   = lane & 15, quad = lane >> 4;
    const int r64  = (wid >> 2) * 64, c64 = (wid & 3) * 64;
    const int r0   = blockIdx.x * 128;

    if (t < 256) { lsum[t] = 0.f; lsq[t] = 0.f; }

    f32x4 acc[4][4];
#pragma unroll
    for (int i = 0; i < 4; ++i)
#pragma unroll
        for (int j = 0; j < 4; ++j) acc[i][j] = (f32x4){0.f, 0.f, 0.f, 0.f};

    for (int k0 = 0; k0 < K; k0 += 32) {
        __syncthreads();
        {   // stage A: 128 rows x 32 k bf16 = 512 uint4, 1/thread
            int row = t >> 2, kq = t & 3;
            uint4 g = make_uint4(0u, 0u, 0u, 0u);
            if (r0 + row < nrows)
                g = *(const uint4*)&A[(size_t)(r0 + row) * K + k0 + kq * 8];
            *(uint4*)&At[row * 40 + kq * 8] = g;
        }
#pragma unroll
        for (int q = 0; q < 2; ++q) {   // stage Bhi/Blo: 256 rows x 32 k each
            int idx = t + 512 * q;
            int row = idx >> 2, kq = idx & 3;
            *(uint4*)&Bh[row * 40 + kq * 8] = *(const uint4*)&Whi[(size_t)row * K + k0 + kq * 8];
            *(uint4*)&Bl[row * 40 + kq * 8] = *(const uint4*)&Wlo[(size_t)row * K + k0 + kq * 8];
        }
        __syncthreads();

        bf16x8 af[4], bh[4], bl[4];
#pragma unroll
        for (int rt = 0; rt < 4; ++rt)
            af[rt] = *(const bf16x8*)&At[(r64 + rt * 16 + ln) * 40 + quad * 8];
#pragma unroll
        for (int ct = 0; ct < 4; ++ct) {
            bh[ct] = *(const bf16x8*)&Bh[(c64 + ct * 16 + ln) * 40 + quad * 8];
            bl[ct] = *(const bf16x8*)&Bl[(c64 + ct * 16 + ln) * 40 + quad * 8];
        }
#pragma unroll
        for (int rt = 0; rt < 4; ++rt)
#pragma unroll
            for (int ct = 0; ct < 4; ++ct) {
                acc[rt][ct] = __builtin_amdgcn_mfma_f32_16x16x32_bf16(af[rt], bh[ct], acc[rt][ct], 0, 0, 0);
                acc[rt][ct] = __builtin_amdgcn_mfma_f32_16x16x32_bf16(af[rt], bl[ct], acc[rt][ct], 0, 0, 0);
            }
    }

    // epilogue: +bias, bf16 store, fused BN stats (pad rows excluded)
    // C/D layout (m89-verified): col = lane&15, row = quad*4 + reg
#pragma unroll
    for (int ct = 0; ct < 4; ++ct) {
        int col = c64 + ct * 16 + ln;
        float bc = bias[col];
        float s = 0.f, qq = 0.f;
#pragma unroll
        for (int rt = 0; rt < 4; ++rt) {
#pragma unroll
            for (int v = 0; v < 4; ++v) {
                int row = r0 + r64 + rt * 16 + quad * 4 + v;
                float val = acc[rt][ct][v] + bc;
                if (row < nrows) {
                    C[(size_t)row * 256 + col] = f2bf(val);
                    s += val; qq += val * val;
                }
            }
        }
        if (do_stats) {
            s  += __shfl_xor(s, 16);  s  += __shfl_xor(s, 32);
            qq += __shfl_xor(qq, 16); qq += __shfl_xor(qq, 32);
            if (quad == 0) { atomicAdd(&lsum[col], s); atomicAdd(&lsq[col], qq); }
        }
    }
    if (do_stats) {
        __syncthreads();
        if (t < 256) { atomicAdd(&bnsum[t], lsum[t]); atomicAdd(&bnsq[t], lsq[t]); }
    }
}

// ---------------------------------------------------------------------------
// Apply: H = relu(T*scale+shift) + 0.2*X (+ 0.7*H);  M (+)= w[l]*H
// BN finalize folded in (scale/shift derived per-block from bnsum/bnsq);
// softmax(res_w) computed per-thread (trivial).
// ---------------------------------------------------------------------------
__global__ void apply_kernel(const unsigned short* __restrict__ T,
                             const unsigned short* __restrict__ X,
                             unsigned short* __restrict__ Hb, unsigned short* __restrict__ M,
                             const float* __restrict__ bnsum, const float* __restrict__ bnsq,
                             const float* __restrict__ gamma, const float* __restrict__ beta,
                             const float* __restrict__ res_w, int layer) {
    __shared__ float sc[256], sh[256];
    int t = threadIdx.x;   // blockDim = 256
    {
        float mean = bnsum[t] * (1.0f / Nn);
        float var  = fmaxf(bnsq[t] * (1.0f / Nn) - mean * mean, 0.f);
        float rstd = rsqrtf(var + 1e-5f);
        float s = gamma[t] * rstd;
        sc[t] = s; sh[t] = beta[t] - mean * s;
    }
    // softmax weight for this layer (redundant per-thread, ~30 flops)
    float m0 = res_w[0];
#pragma unroll
    for (int i = 1; i < Lnum; ++i) m0 = fmaxf(m0, res_w[i]);
    float se = 0.f, wl = 0.f;
#pragma unroll
    for (int i = 0; i < Lnum; ++i) {
        float e = __expf(res_w[i] - m0);
        se += e;
        if (i == layer) wl = e;
    }
    float wi = wl / se;
    __syncthreads();

    int idx = blockIdx.x * blockDim.x + t;   // uint4 index, Nn*32 total
    int c8 = idx & 31;
    float scl[8], shl[8];
#pragma unroll
    for (int k = 0; k < 8; ++k) { scl[k] = sc[c8 * 8 + k]; shl[k] = sh[c8 * 8 + k]; }

    uint4 tv = ((const uint4*)T)[idx];
    uint4 xv = ((const uint4*)X)[idx];
    float tf[8], xf[8];
    unpack2(tv.x, tf[0], tf[1]); unpack2(tv.y, tf[2], tf[3]);
    unpack2(tv.z, tf[4], tf[5]); unpack2(tv.w, tf[6], tf[7]);
    unpack2(xv.x, xf[0], xf[1]); unpack2(xv.y, xf[2], xf[3]);
    unpack2(xv.z, xf[4], xf[5]); unpack2(xv.w, xf[6], xf[7]);

    float a[8];
#pragma unroll
    for (int k = 0; k < 8; ++k)
        a[k] = fmaxf(tf[k] * scl[k] + shl[k], 0.f) + 0.2f * xf[k];
    if (layer > 0) {
        uint4 hv = ((const uint4*)Hb)[idx];
        float hf[8];
        unpack2(hv.x, hf[0], hf[1]); unpack2(hv.y, hf[2], hf[3]);
        unpack2(hv.z, hf[4], hf[5]); unpack2(hv.w, hf[6], hf[7]);
#pragma unroll
        for (int k = 0; k < 8; ++k) a[k] += 0.7f * hf[k];
    }
    uint4 ho;
    ho.x = pack2(a[0], a[1]); ho.y = pack2(a[2], a[3]);
    ho.z = pack2(a[4], a[5]); ho.w = pack2(a[6], a[7]);
    ((uint4*)Hb)[idx] = ho;

    float m[8];
    if (layer == 0) {
#pragma unroll
        for (int k = 0; k < 8; ++k) m[k] = wi * a[k];
    } else {
        uint4 mv = ((const uint4*)M)[idx];
        float mf[8];
        unpack2(mv.x, mf[0], mf[1]); unpack2(mv.y, mf[2], mf[3]);
        unpack2(mv.z, mf[4], mf[5]); unpack2(mv.w, mf[6], mf[7]);
#pragma unroll
        for (int k = 0; k < 8; ++k) m[k] = mf[k] + wi * a[k];
    }
    uint4 mo;
    mo.x = pack2(m[0], m[1]); mo.y = pack2(m[2], m[3]);
    mo.z = pack2(m[4], m[5]); mo.w = pack2(m[6], m[7]);
    ((uint4*)M)[idx] = mo;
}

// ---------------------------------------------------------------------------
// Head: logits = M @ out_w + out_b ; log_softmax per row. 16 rows/block.
// ---------------------------------------------------------------------------
#define HBR 16
__global__ __launch_bounds__(128) void head_kernel(const unsigned short* __restrict__ M,
                                                   const float* __restrict__ out_w,
                                                   const float* __restrict__ out_b,
                                                   float* __restrict__ out) {
    __shared__ float wl[256 * 40];
    __shared__ float rows[HBR * 257];
    int t = threadIdx.x;
    int r0 = blockIdx.x * HBR;
#pragma unroll
    for (int q = 0; q < 20; ++q) {
        int qid = t + 128 * q;
        *(float4*)&wl[qid * 4] = *(const float4*)&out_w[qid * 4];
    }
#pragma unroll
    for (int q = 0; q < 4; ++q) {
        int qid = t + 128 * q;
        int r = qid >> 5, c = qid & 31;
        uint4 g = *(const uint4*)&M[(size_t)(r0 + r) * 256 + c * 8];
        float f[8];
        unpack2(g.x, f[0], f[1]); unpack2(g.y, f[2], f[3]);
        unpack2(g.z, f[4], f[5]); unpack2(g.w, f[6], f[7]);
#pragma unroll
        for (int k = 0; k < 8; ++k) rows[r * 257 + c * 8 + k] = f[k];
    }
    __syncthreads();
    int r = t >> 3, g8 = t & 7, c0 = g8 * 5;
    float acc[5];
#pragma unroll
    for (int j = 0; j < 5; ++j) acc[j] = out_b[c0 + j];
    for (int k = 0; k < 256; ++k) {
        float m = rows[r * 257 + k];
#pragma unroll
        for (int j = 0; j < 5; ++j) acc[j] += m * wl[k * 40 + c0 + j];
    }
    float mx = acc[0];
#pragma unroll
    for (int j = 1; j < 5; ++j) mx = fmaxf(mx, acc[j]);
    for (int d = 1; d < 8; d <<= 1) mx = fmaxf(mx, __shfl_xor(mx, d));
    float s = 0.f;
#pragma unroll
    for (int j = 0; j < 5; ++j) s += expf(acc[j] - mx);
    for (int d = 1; d < 8; d <<= 1) s += __shfl_xor(s, d);
    float lse = mx + logf(s);
#pragma unroll
    for (int j = 0; j < 5; ++j)
        out[(size_t)(r0 + r) * 40 + c0 + j] = acc[j] - lse;
}

// ---------------------------------------------------------------------------
extern "C" void kernel_launch(void* const* d_in, const int* in_sizes, int n_in,
                              void* d_out, int out_size, void* d_ws, size_t ws_size,
                              hipStream_t stream)
{
    const float* x      = (const float*)d_in[0];
    const int*   ei     = (const int*)d_in[1];
    const float* w_in   = (const float*)d_in[2];
    const float* b_in   = (const float*)d_in[3];
    const float* conv_w = (const float*)d_in[4];
    const float* conv_b = (const float*)d_in[5];
    const float* gamma  = (const float*)d_in[6];
    const float* beta   = (const float*)d_in[7];
    const float* out_w  = (const float*)d_in[8];
    const float* out_b  = (const float*)d_in[9];
    const float* res_w  = (const float*)d_in[10];
    float* out = (float*)d_out;
    char* ws = (char*)d_ws;

    // workspace layout (total ~211 MB), all offsets 16B-aligned
    int*   cnt    = (int*)  (ws + 0);
    int*   cursor = (int*)  (ws + 400000);
    int*   offs   = (int*)  (ws + 800000);
    float* dinvp  = (float*)(ws + 1200016);
    int*   esrc   = (int*)  (ws + 1600016);
    float* ew     = (float*)(ws + 2800016);
    float* bnsum  = (float*)(ws + 4000016);
    float* bnsq   = (float*)(ws + 4001040);
    int*   iscan  = (int*)  (ws + 4002064);
    int*   btot   = (int*)  (ws + 4402064);
    int*   bpref  = (int*)  (ws + 4402576);
    unsigned short* Whi = (unsigned short*)(ws + 4403088);   // [L][256][256] bf16
    unsigned short* Wlo = (unsigned short*)(ws + 5189520);
    unsigned short* Fhi = (unsigned short*)(ws + 5975952);   // [256][128] bf16
    unsigned short* Flo = (unsigned short*)(ws + 6041488);
    unsigned short* X   = (unsigned short*)(ws + 6107024);   // N*H bf16 = 51.2 MB each
    unsigned short* Hb  = X  + (size_t)Nn * Hdim;
    unsigned short* T   = Hb + (size_t)Nn * Hdim;
    unsigned short* M   = T  + (size_t)Nn * Hdim;
    unsigned short* xbf = M;   // scratch alias: fc input, dead before M first written

    hipMemsetAsync(cnt, 0, 800000, stream);  // cnt + cursor

    count_edges<<<(Ee + 255) / 256, 256, 0, stream>>>(ei, cnt);
    scan_block<<<SCAN_B, 1024, 0, stream>>>(cnt, iscan, btot);
    scan_tops<<<1, 128, 0, stream>>>(btot, bpref);
    scan_final<<<SCAN_B, 1024, 0, stream>>>(cnt, iscan, bpref, offs, dinvp);
    fill_csr<<<(Ee + 255) / 256, 256, 0, stream>>>(ei, offs, cursor, dinvp, esrc, ew);

    // weight split+transpose
    split_w_all<<<(Lnum * 65536) / 256, 256, 0, stream>>>(conv_w, Whi, Wlo);
    split_w<<<(FIN * 256) / 256, 256, 0, stream>>>(w_in, Fhi, Flo, FIN);
    cvt_bf16<<<(Nn * FIN / 8 + 255) / 256, 256, 0, stream>>>(x, xbf, Nn * FIN / 8);

    const int gblocks = (Nn + 127) / 128;   // 782
    // input fc: X = xbf @ w_in + b_in
    gemm_mfma<<<gblocks, 512, 0, stream>>>(xbf, X, Fhi, Flo, b_in, FIN, Nn,
                                           nullptr, nullptr, 0);

    for (int i = 0; i < Lnum; ++i) {
        agg_kernel<<<Nn, 128, 0, stream>>>(i == 0 ? X : Hb, T, offs, esrc, ew, dinvp,
                                           bnsum, bnsq);
        gemm_mfma<<<gblocks, 512, 0, stream>>>(T, T,
                                               Whi + (size_t)i * Hdim * Hdim,
                                               Wlo + (size_t)i * Hdim * Hdim,
                                               conv_b + (size_t)i * Hdim,
                                               Hdim, Nn, bnsum, bnsq, 1);
        apply_kernel<<<(Nn * 32) / 256, 256, 0, stream>>>(T, X, Hb, M,
                                                          bnsum, bnsq,
                                                          gamma + (size_t)i * Hdim,
                                                          beta + (size_t)i * Hdim,
                                                          res_w, i);
    }

    head_kernel<<<Nn / HBR, 128, 0, stream>>>(M, out_w, out_b, out);
}

// Round 5
// 1301.821 us; speedup vs baseline: 1.9617x; 1.0662x over previous
//
#include <hip/hip_runtime.h>
#include <math.h>

// Problem constants (from reference)
#define Nn   100000
#define Ee   300000
#define FIN  128
#define Hdim 256
#define Ncls 40
#define Lnum 6
#define SCAN_B 98   // ceil(Nn/1024)

typedef __attribute__((ext_vector_type(8))) short bf16x8;
typedef __attribute__((ext_vector_type(4))) float f32x4;

// ---------------- bf16 helpers (storage bf16, compute fp32) ----------------
__device__ __forceinline__ float bf2f(unsigned int u16) {
    unsigned int x = u16 << 16;
    return __builtin_bit_cast(float, x);
}
__device__ __forceinline__ unsigned short f2bf(float f) {
    unsigned int x = __builtin_bit_cast(unsigned int, f);
    x = (x + 0x7FFFu + ((x >> 16) & 1u)) >> 16;   // round-nearest-even
    return (unsigned short)x;
}
__device__ __forceinline__ void unpack2(unsigned int u, float& lo, float& hi) {
    lo = __builtin_bit_cast(float, u << 16);
    hi = __builtin_bit_cast(float, u & 0xFFFF0000u);
}
__device__ __forceinline__ unsigned int pack2(float a, float b) {
    return (unsigned int)f2bf(a) | ((unsigned int)f2bf(b) << 16);
}

// ---------------------------------------------------------------------------
// Graph preprocessing
// ---------------------------------------------------------------------------
__global__ void count_edges(const int* __restrict__ ei, int* __restrict__ cnt) {
    int e = blockIdx.x * blockDim.x + threadIdx.x;
    if (e < Ee) atomicAdd(&cnt[ei[Ee + e]], 1);   // row 1 of edge_index = dst
}

__global__ void scan_block(const int* __restrict__ cnt, int* __restrict__ iscan,
                           int* __restrict__ btot) {
    __shared__ int buf[1024];
    int t = threadIdx.x;
    int g = blockIdx.x * 1024 + t;
    int v = (g < Nn) ? cnt[g] : 0;
    buf[t] = v; __syncthreads();
    for (int off = 1; off < 1024; off <<= 1) {
        int x = buf[t];
        int a = (t >= off) ? buf[t - off] : 0;
        __syncthreads();
        buf[t] = x + a;
        __syncthreads();
    }
    if (g < Nn) iscan[g] = buf[t];
    if (t == 1023) btot[blockIdx.x] = buf[1023];
}

__global__ void scan_tops(const int* __restrict__ btot, int* __restrict__ bpref) {
    __shared__ int b[128];
    int t = threadIdx.x;
    int v = (t < SCAN_B) ? btot[t] : 0;
    b[t] = v; __syncthreads();
    for (int off = 1; off < 128; off <<= 1) {
        int x = b[t];
        int a = (t >= off) ? b[t - off] : 0;
        __syncthreads();
        b[t] = x + a;
        __syncthreads();
    }
    if (t < SCAN_B) bpref[t] = b[t] - v;   // exclusive
}

__global__ void scan_final(const int* __restrict__ cnt, const int* __restrict__ iscan,
                           const int* __restrict__ bpref, int* __restrict__ offs,
                           float* __restrict__ dinvp) {
    int g = blockIdx.x * 1024 + threadIdx.x;
    if (g < Nn) {
        int c = cnt[g];
        offs[g] = bpref[blockIdx.x] + iscan[g] - c;
        dinvp[g] = rsqrtf((float)(c + 1));    // deg = in-deg + self-loop
    }
    if (g == 0) offs[Nn] = Ee;
}

__global__ void fill_csr(const int* __restrict__ ei, const int* __restrict__ offs,
                         int* __restrict__ cur, const float* __restrict__ dinvp,
                         int* __restrict__ esrc, float* __restrict__ ew) {
    int e = blockIdx.x * blockDim.x + threadIdx.x;
    if (e >= Ee) return;
    int s = ei[e], d = ei[Ee + e];
    int p = offs[d] + atomicAdd(&cur[d], 1);
    esrc[p] = s;
    ew[p] = dinvp[s];
}

// ---------------------------------------------------------------------------
// All weight prep in ONE dispatch (blockIdx ranges):
//  blocks [0,1536)    : conv_w [L][256][256] -> Whi/Wlo [L][256(n)][256(k)]
//  blocks [1536,1664) : w_in [128][256]      -> Fhi/Flo [256(n)][128(k)]
//  blocks [1664,1712) : out_w [256][40]      -> Whd/Wld [48(c,pad)][256(k)]
// ---------------------------------------------------------------------------
__global__ void prep_weights(const float* __restrict__ conv_w, const float* __restrict__ w_in,
                             const float* __restrict__ out_w,
                             unsigned short* __restrict__ Whi, unsigned short* __restrict__ Wlo,
                             unsigned short* __restrict__ Fhi, unsigned short* __restrict__ Flo,
                             unsigned short* __restrict__ Whd, unsigned short* __restrict__ Wld) {
    int b = blockIdx.x, t = threadIdx.x;
    if (b < 1536) {
        int id = b * 256 + t;                    // [0, 393216)
        int l = id >> 16, k = (id >> 8) & 255, n = id & 255;
        float w = conv_w[id];
        unsigned short hi = f2bf(w);
        unsigned short lo = f2bf(w - bf2f(hi));
        Whi[l * 65536 + n * 256 + k] = hi;
        Wlo[l * 65536 + n * 256 + k] = lo;
    } else if (b < 1664) {
        int id = (b - 1536) * 256 + t;           // [0, 32768)
        int k = id >> 8, n = id & 255;
        float w = w_in[id];
        unsigned short hi = f2bf(w);
        unsigned short lo = f2bf(w - bf2f(hi));
        Fhi[n * FIN + k] = hi;
        Flo[n * FIN + k] = lo;
    } else {
        int id = (b - 1664) * 256 + t;           // [0, 12288)
        int c = id >> 8, k = id & 255;
        float w = (c < Ncls) ? out_w[k * Ncls + c] : 0.f;
        unsigned short hi = f2bf(w);
        unsigned short lo = f2bf(w - bf2f(hi));
        Whd[c * 256 + k] = hi;
        Wld[c * 256 + k] = lo;
    }
}

// x fp32 -> bf16 (8 elems/thread)
__global__ void cvt_bf16(const float* __restrict__ src, unsigned short* __restrict__ dst, int n8) {
    int i = blockIdx.x * blockDim.x + threadIdx.x;
    if (i >= n8) return;
    float4 a = ((const float4*)src)[i * 2];
    float4 b = ((const float4*)src)[i * 2 + 1];
    uint4 o;
    o.x = pack2(a.x, a.y); o.y = pack2(a.z, a.w);
    o.z = pack2(b.x, b.y); o.w = pack2(b.z, b.w);
    ((uint4*)dst)[i] = o;
}

// ---------------------------------------------------------------------------
// Aggregation: wave-per-node, 4 nodes/block (256 thr), 4 feats/lane (uint2).
// T[n] = dinv[n]*(sum_e w_e*H[src] + dinv[n]*H[n]). Block 0 zeroes BN stats.
// ---------------------------------------------------------------------------
__global__ void agg_kernel(const unsigned short* __restrict__ Hin,
                           unsigned short* __restrict__ T,
                           const int* __restrict__ offs, const int* __restrict__ esrc,
                           const float* __restrict__ ew, const float* __restrict__ dinvp,
                           float* __restrict__ bnsum, float* __restrict__ bnsq) {
    int t = threadIdx.x;
    if (blockIdx.x == 0) { bnsum[t] = 0.f; bnsq[t] = 0.f; }   // blockDim==256
    int wv = t >> 6, lane = t & 63;
    int n = blockIdx.x * 4 + wv;          // grid = Nn/4 exact
    int o0 = offs[n], o1 = offs[n + 1];
    float dn = dinvp[n];
    uint2 u = *(const uint2*)&Hin[(size_t)n * Hdim + lane * 4];
    float a0, a1, a2, a3;
    unpack2(u.x, a0, a1); unpack2(u.y, a2, a3);
    a0 *= dn; a1 *= dn; a2 *= dn; a3 *= dn;
    for (int e = o0; e < o1; ++e) {
        int s = esrc[e];
        float w = ew[e];
        uint2 us = *(const uint2*)&Hin[(size_t)s * Hdim + lane * 4];
        float v0, v1, v2, v3;
        unpack2(us.x, v0, v1); unpack2(us.y, v2, v3);
        a0 += w * v0; a1 += w * v1; a2 += w * v2; a3 += w * v3;
    }
    uint2 o;
    o.x = pack2(dn * a0, dn * a1); o.y = pack2(dn * a2, dn * a3);
    *(uint2*)&T[(size_t)n * Hdim + lane * 4] = o;
}

// ---------------------------------------------------------------------------
// MFMA GEMM: C[M,256] = A[M,K] @ (Whi+Wlo)[K,256] + bias (bf16 storage,
// fp32 accum; W transposed [256][K] hi/lo split). 128x256 block, 8 waves.
// ---------------------------------------------------------------------------
__global__ __launch_bounds__(512) void gemm_mfma(
    const unsigned short* __restrict__ A, unsigned short* __restrict__ C,
    const unsigned short* __restrict__ Whi, const unsigned short* __restrict__ Wlo,
    const float* __restrict__ bias, int K, int nrows,
    float* __restrict__ bnsum, float* __restrict__ bnsq, int do_stats)
{
    __shared__ unsigned short At[128 * 40];   // 10 KB
    __shared__ unsigned short Bh[256 * 40];   // 20 KB
    __shared__ unsigned short Bl[256 * 40];   // 20 KB
    __shared__ float lsum[256];
    __shared__ float lsq[256];

    const int t    = threadIdx.x;
    const int lane = t & 63, wid = t >> 6;
    const int ln   = lane & 15, quad = lane >> 4;
    const int r64  = (wid >> 2) * 64, c64 = (wid & 3) * 64;
    const int r0   = blockIdx.x * 128;

    if (t < 256) { lsum[t] = 0.f; lsq[t] = 0.f; }

    f32x4 acc[4][4];
#pragma unroll
    for (int i = 0; i < 4; ++i)
#pragma unroll
        for (int j = 0; j < 4; ++j) acc[i][j] = (f32x4){0.f, 0.f, 0.f, 0.f};

    for (int k0 = 0; k0 < K; k0 += 32) {
        __syncthreads();
        {   // stage A: 128 rows x 32 k bf16 = 512 uint4, 1/thread
            int row = t >> 2, kq = t & 3;
            uint4 g = make_uint4(0u, 0u, 0u, 0u);
            if (r0 + row < nrows)
                g = *(const uint4*)&A[(size_t)(r0 + row) * K + k0 + kq * 8];
            *(uint4*)&At[row * 40 + kq * 8] = g;
        }
#pragma unroll
        for (int q = 0; q < 2; ++q) {   // stage Bhi/Blo: 256 rows x 32 k each
            int idx = t + 512 * q;
            int row = idx >> 2, kq = idx & 3;
            *(uint4*)&Bh[row * 40 + kq * 8] = *(const uint4*)&Whi[(size_t)row * K + k0 + kq * 8];
            *(uint4*)&Bl[row * 40 + kq * 8] = *(const uint4*)&Wlo[(size_t)row * K + k0 + kq * 8];
        }
        __syncthreads();

        bf16x8 af[4], bh[4], bl[4];
#pragma unroll
        for (int rt = 0; rt < 4; ++rt)
            af[rt] = *(const bf16x8*)&At[(r64 + rt * 16 + ln) * 40 + quad * 8];
#pragma unroll
        for (int ct = 0; ct < 4; ++ct) {
            bh[ct] = *(const bf16x8*)&Bh[(c64 + ct * 16 + ln) * 40 + quad * 8];
            bl[ct] = *(const bf16x8*)&Bl[(c64 + ct * 16 + ln) * 40 + quad * 8];
        }
#pragma unroll
        for (int rt = 0; rt < 4; ++rt)
#pragma unroll
            for (int ct = 0; ct < 4; ++ct) {
                acc[rt][ct] = __builtin_amdgcn_mfma_f32_16x16x32_bf16(af[rt], bh[ct], acc[rt][ct], 0, 0, 0);
                acc[rt][ct] = __builtin_amdgcn_mfma_f32_16x16x32_bf16(af[rt], bl[ct], acc[rt][ct], 0, 0, 0);
            }
    }

    // epilogue: +bias, bf16 store, fused BN stats (pad rows excluded)
    // C/D layout (m89-verified): col = lane&15, row = quad*4 + reg
#pragma unroll
    for (int ct = 0; ct < 4; ++ct) {
        int col = c64 + ct * 16 + ln;
        float bc = bias[col];
        float s = 0.f, qq = 0.f;
#pragma unroll
        for (int rt = 0; rt < 4; ++rt) {
#pragma unroll
            for (int v = 0; v < 4; ++v) {
                int row = r0 + r64 + rt * 16 + quad * 4 + v;
                float val = acc[rt][ct][v] + bc;
                if (row < nrows) {
                    C[(size_t)row * 256 + col] = f2bf(val);
                    s += val; qq += val * val;
                }
            }
        }
        if (do_stats) {
            s  += __shfl_xor(s, 16);  s  += __shfl_xor(s, 32);
            qq += __shfl_xor(qq, 16); qq += __shfl_xor(qq, 32);
            if (quad == 0) { atomicAdd(&lsum[col], s); atomicAdd(&lsq[col], qq); }
        }
    }
    if (do_stats) {
        __syncthreads();
        if (t < 256) { atomicAdd(&bnsum[t], lsum[t]); atomicAdd(&bnsq[t], lsq[t]); }
    }
}

// ---------------------------------------------------------------------------
// Apply: H = relu(T*scale+shift) + 0.2*X (+ 0.7*H);  M (+)= w[l]*H
// BN finalize + res-softmax folded in.
// ---------------------------------------------------------------------------
__global__ void apply_kernel(const unsigned short* __restrict__ T,
                             const unsigned short* __restrict__ X,
                             unsigned short* __restrict__ Hb, unsigned short* __restrict__ M,
                             const float* __restrict__ bnsum, const float* __restrict__ bnsq,
                             const float* __restrict__ gamma, const float* __restrict__ beta,
                             const float* __restrict__ res_w, int layer) {
    __shared__ float sc[256], sh[256];
    int t = threadIdx.x;   // blockDim = 256
    {
        float mean = bnsum[t] * (1.0f / Nn);
        float var  = fmaxf(bnsq[t] * (1.0f / Nn) - mean * mean, 0.f);
        float rstd = rsqrtf(var + 1e-5f);
        float s = gamma[t] * rstd;
        sc[t] = s; sh[t] = beta[t] - mean * s;
    }
    float m0 = res_w[0];
#pragma unroll
    for (int i = 1; i < Lnum; ++i) m0 = fmaxf(m0, res_w[i]);
    float se = 0.f, wl = 0.f;
#pragma unroll
    for (int i = 0; i < Lnum; ++i) {
        float e = __expf(res_w[i] - m0);
        se += e;
        if (i == layer) wl = e;
    }
    float wi = wl / se;
    __syncthreads();

    int idx = blockIdx.x * blockDim.x + t;   // uint4 index, Nn*32 total
    int c8 = idx & 31;
    float scl[8], shl[8];
#pragma unroll
    for (int k = 0; k < 8; ++k) { scl[k] = sc[c8 * 8 + k]; shl[k] = sh[c8 * 8 + k]; }

    uint4 tv = ((const uint4*)T)[idx];
    uint4 xv = ((const uint4*)X)[idx];
    float tf[8], xf[8];
    unpack2(tv.x, tf[0], tf[1]); unpack2(tv.y, tf[2], tf[3]);
    unpack2(tv.z, tf[4], tf[5]); unpack2(tv.w, tf[6], tf[7]);
    unpack2(xv.x, xf[0], xf[1]); unpack2(xv.y, xf[2], xf[3]);
    unpack2(xv.z, xf[4], xf[5]); unpack2(xv.w, xf[6], xf[7]);

    float a[8];
#pragma unroll
    for (int k = 0; k < 8; ++k)
        a[k] = fmaxf(tf[k] * scl[k] + shl[k], 0.f) + 0.2f * xf[k];
    if (layer > 0) {
        uint4 hv = ((const uint4*)Hb)[idx];
        float hf[8];
        unpack2(hv.x, hf[0], hf[1]); unpack2(hv.y, hf[2], hf[3]);
        unpack2(hv.z, hf[4], hf[5]); unpack2(hv.w, hf[6], hf[7]);
#pragma unroll
        for (int k = 0; k < 8; ++k) a[k] += 0.7f * hf[k];
    }
    uint4 ho;
    ho.x = pack2(a[0], a[1]); ho.y = pack2(a[2], a[3]);
    ho.z = pack2(a[4], a[5]); ho.w = pack2(a[6], a[7]);
    ((uint4*)Hb)[idx] = ho;

    float m[8];
    if (layer == 0) {
#pragma unroll
        for (int k = 0; k < 8; ++k) m[k] = wi * a[k];
    } else {
        uint4 mv = ((const uint4*)M)[idx];
        float mf[8];
        unpack2(mv.x, mf[0], mf[1]); unpack2(mv.y, mf[2], mf[3]);
        unpack2(mv.z, mf[4], mf[5]); unpack2(mv.w, mf[6], mf[7]);
#pragma unroll
        for (int k = 0; k < 8; ++k) m[k] = mf[k] + wi * a[k];
    }
    uint4 mo;
    mo.x = pack2(m[0], m[1]); mo.y = pack2(m[2], m[3]);
    mo.z = pack2(m[4], m[5]); mo.w = pack2(m[6], m[7]);
    ((uint4*)M)[idx] = mo;
}

// ---------------------------------------------------------------------------
// Head via MFMA: logits[N,40] = M @ out_w + out_b, log_softmax rows.
// 128 rows/block, 512 thr = 8 waves (16 rows each), 48 padded cols = 3 tiles.
// B frags loaded straight from L2 (Wt is 48x256 hi/lo). 10 KB LDS.
// ---------------------------------------------------------------------------
__global__ __launch_bounds__(512) void head_mfma(const unsigned short* __restrict__ M,
                                                 const unsigned short* __restrict__ Whd,
                                                 const unsigned short* __restrict__ Wld,
                                                 const float* __restrict__ out_b,
                                                 float* __restrict__ out, int nrows) {
    __shared__ unsigned short At[128 * 40];   // 10 KB
    const int t    = threadIdx.x;
    const int lane = t & 63, wid = t >> 6;
    const int ln   = lane & 15, quad = lane >> 4;
    const int r0   = blockIdx.x * 128;

    f32x4 acc[3];
#pragma unroll
    for (int ct = 0; ct < 3; ++ct) acc[ct] = (f32x4){0.f, 0.f, 0.f, 0.f};

    for (int k0 = 0; k0 < 256; k0 += 32) {
        __syncthreads();
        {   // stage A: 128 rows x 32 k = 512 uint4, 1/thread
            int row = t >> 2, kq = t & 3;
            uint4 g = make_uint4(0u, 0u, 0u, 0u);
            if (r0 + row < nrows)
                g = *(const uint4*)&M[(size_t)(r0 + row) * 256 + k0 + kq * 8];
            *(uint4*)&At[row * 40 + kq * 8] = g;
        }
        __syncthreads();
        bf16x8 af = *(const bf16x8*)&At[(wid * 16 + ln) * 40 + quad * 8];
#pragma unroll
        for (int ct = 0; ct < 3; ++ct) {
            int c = ct * 16 + ln;
            bf16x8 bh = *(const bf16x8*)&Whd[c * 256 + k0 + quad * 8];
            bf16x8 bl = *(const bf16x8*)&Wld[c * 256 + k0 + quad * 8];
            acc[ct] = __builtin_amdgcn_mfma_f32_16x16x32_bf16(af, bh, acc[ct], 0, 0, 0);
            acc[ct] = __builtin_amdgcn_mfma_f32_16x16x32_bf16(af, bl, acc[ct], 0, 0, 0);
        }
    }

    // epilogue: bias, per-row log-softmax via 16-lane butterfly, store
    int   cc[3]; float bias[3];
#pragma unroll
    for (int ct = 0; ct < 3; ++ct) {
        cc[ct] = ct * 16 + ln;
        bias[ct] = (cc[ct] < Ncls) ? out_b[cc[ct]] : 0.f;
    }
#pragma unroll
    for (int v = 0; v < 4; ++v) {
        int row = r0 + wid * 16 + quad * 4 + v;
        float val[3];
#pragma unroll
        for (int ct = 0; ct < 3; ++ct) val[ct] = acc[ct][v] + bias[ct];
        float mx = -1e30f;
#pragma unroll
        for (int ct = 0; ct < 3; ++ct) if (cc[ct] < Ncls) mx = fmaxf(mx, val[ct]);
        mx = fmaxf(mx, __shfl_xor(mx, 1)); mx = fmaxf(mx, __shfl_xor(mx, 2));
        mx = fmaxf(mx, __shfl_xor(mx, 4)); mx = fmaxf(mx, __shfl_xor(mx, 8));
        float s = 0.f;
#pragma unroll
        for (int ct = 0; ct < 3; ++ct) if (cc[ct] < Ncls) s += __expf(val[ct] - mx);
        s += __shfl_xor(s, 1); s += __shfl_xor(s, 2);
        s += __shfl_xor(s, 4); s += __shfl_xor(s, 8);
        float lse = mx + __logf(s);
        if (row < nrows) {
            out[(size_t)row * Ncls + cc[0]] = val[0] - lse;
            out[(size_t)row * Ncls + cc[1]] = val[1] - lse;
            if (ln < 8) out[(size_t)row * Ncls + cc[2]] = val[2] - lse;
        }
    }
}

// ---------------------------------------------------------------------------
extern "C" void kernel_launch(void* const* d_in, const int* in_sizes, int n_in,
                              void* d_out, int out_size, void* d_ws, size_t ws_size,
                              hipStream_t stream)
{
    const float* x      = (const float*)d_in[0];
    const int*   ei     = (const int*)d_in[1];
    const float* w_in   = (const float*)d_in[2];
    const float* b_in   = (const float*)d_in[3];
    const float* conv_w = (const float*)d_in[4];
    const float* conv_b = (const float*)d_in[5];
    const float* gamma  = (const float*)d_in[6];
    const float* beta   = (const float*)d_in[7];
    const float* out_w  = (const float*)d_in[8];
    const float* out_b  = (const float*)d_in[9];
    const float* res_w  = (const float*)d_in[10];
    float* out = (float*)d_out;
    char* ws = (char*)d_ws;

    // workspace layout (total ~211 MB), 16B-aligned slots
    int*   cnt    = (int*)  (ws + 0);
    int*   cursor = (int*)  (ws + 400000);
    int*   offs   = (int*)  (ws + 800000);
    float* dinvp  = (float*)(ws + 1200016);
    int*   esrc   = (int*)  (ws + 1600016);
    float* ew     = (float*)(ws + 2800016);
    float* bnsum  = (float*)(ws + 4000016);
    float* bnsq   = (float*)(ws + 4001040);
    int*   iscan  = (int*)  (ws + 4002064);
    int*   btot   = (int*)  (ws + 4402064);
    int*   bpref  = (int*)  (ws + 4402576);
    unsigned short* Whi = (unsigned short*)(ws + 4403088);   // [L][256][256] bf16
    unsigned short* Wlo = (unsigned short*)(ws + 5189520);
    unsigned short* Fhi = (unsigned short*)(ws + 5975952);   // [256][128] bf16
    unsigned short* Flo = (unsigned short*)(ws + 6041488);
    unsigned short* Whd = (unsigned short*)(ws + 6107024);   // [48][256] bf16
    unsigned short* Wld = (unsigned short*)(ws + 6131600);
    unsigned short* X   = (unsigned short*)(ws + 6156176);   // N*H bf16 = 51.2 MB each
    unsigned short* Hb  = X  + (size_t)Nn * Hdim;
    unsigned short* T   = Hb + (size_t)Nn * Hdim;
    unsigned short* M   = T  + (size_t)Nn * Hdim;
    unsigned short* xbf = M;   // scratch alias: fc input, dead before M first written

    hipMemsetAsync(cnt, 0, 800000, stream);  // cnt + cursor

    count_edges<<<(Ee + 255) / 256, 256, 0, stream>>>(ei, cnt);
    scan_block<<<SCAN_B, 1024, 0, stream>>>(cnt, iscan, btot);
    scan_tops<<<1, 128, 0, stream>>>(btot, bpref);
    scan_final<<<SCAN_B, 1024, 0, stream>>>(cnt, iscan, bpref, offs, dinvp);
    fill_csr<<<(Ee + 255) / 256, 256, 0, stream>>>(ei, offs, cursor, dinvp, esrc, ew);

    prep_weights<<<1712, 256, 0, stream>>>(conv_w, w_in, out_w,
                                           Whi, Wlo, Fhi, Flo, Whd, Wld);
    cvt_bf16<<<(Nn * FIN / 8 + 255) / 256, 256, 0, stream>>>(x, xbf, Nn * FIN / 8);

    const int gblocks = (Nn + 127) / 128;   // 782
    gemm_mfma<<<gblocks, 512, 0, stream>>>(xbf, X, Fhi, Flo, b_in, FIN, Nn,
                                           nullptr, nullptr, 0);

    for (int i = 0; i < Lnum; ++i) {
        agg_kernel<<<Nn / 4, 256, 0, stream>>>(i == 0 ? X : Hb, T, offs, esrc, ew, dinvp,
                                               bnsum, bnsq);
        gemm_mfma<<<gblocks, 512, 0, stream>>>(T, T,
                                               Whi + (size_t)i * Hdim * Hdim,
                                               Wlo + (size_t)i * Hdim * Hdim,
                                               conv_b + (size_t)i * Hdim,
                                               Hdim, Nn, bnsum, bnsq, 1);
        apply_kernel<<<(Nn * 32) / 256, 256, 0, stream>>>(T, X, Hb, M,
                                                          bnsum, bnsq,
                                                          gamma + (size_t)i * Hdim,
                                                          beta + (size_t)i * Hdim,
                                                          res_w, i);
    }

    head_mfma<<<gblocks, 512, 0, stream>>>(M, Whd, Wld, out_b, out, Nn);
}